// Round 10
// baseline (605.422 us; speedup 1.0000x reference)
//
#include <hip/hip_runtime.h>

#define R_ 3
#define N_ 50000
#define E_ 800000
#define DIN 128
#define DOUT 64
#define RT (R_ * N_)          // 150000 output rows total
#define SCAN_NB ((RT + 1023) / 1024)  // 147 scan blocks

// ---------------------------------------------------------------------------
// K1: support[r] = X[r] @ W[r]   (fp32 vector GEMM, M=50000, K=128, N=64)
// ---------------------------------------------------------------------------
__global__ __launch_bounds__(256) void gemm_kernel(const float* __restrict__ X,
                                                   const float* __restrict__ W,
                                                   float* __restrict__ support) {
  const int r = blockIdx.y;
  const int base = blockIdx.x * 256;
  const int t = threadIdx.x;

  __shared__ float x_s[32 * 258];

  const float* Xr = X + (size_t)r * N_ * DIN;
  const float* Wr = W + (size_t)r * DIN * DOUT;

  float acc[DOUT];
#pragma unroll
  for (int o = 0; o < DOUT; ++o) acc[o] = 0.f;

  for (int k0 = 0; k0 < DIN; k0 += 32) {
    __syncthreads();
#pragma unroll
    for (int i = 0; i < 8; ++i) {
      int rl = i * 32 + (t >> 3);
      int k4 = (t & 7) * 4;
      int rg = base + rl;
      if (rg > N_ - 1) rg = N_ - 1;
      const float4 v = *(const float4*)(Xr + (size_t)rg * DIN + k0 + k4);
      x_s[(k4 + 0) * 258 + rl] = v.x;
      x_s[(k4 + 1) * 258 + rl] = v.y;
      x_s[(k4 + 2) * 258 + rl] = v.z;
      x_s[(k4 + 3) * 258 + rl] = v.w;
    }
    __syncthreads();
#pragma unroll 4
    for (int kk = 0; kk < 32; ++kk) {
      const float xv = x_s[kk * 258 + t];
      const float* wrow = Wr + (size_t)(k0 + kk) * DOUT;  // wave-uniform -> s_load
#pragma unroll
      for (int o = 0; o < DOUT; ++o) acc[o] = fmaf(wrow[o], xv, acc[o]);
    }
  }

  const int row = base + t;
  if (row < N_) {
    float* op = support + ((size_t)r * N_ + row) * DOUT;
#pragma unroll
    for (int o = 0; o < DOUT; o += 4) {
      float4 v = {acc[o], acc[o + 1], acc[o + 2], acc[o + 3]};
      *(float4*)(op + o) = v;
    }
  }
}

// ---------------------------------------------------------------------------
// K2: histogram of destination rows: cnt[r*N + rows[e]]++
// (fire-and-forget atomics, no return dependency -> never in top-5; unchanged)
// ---------------------------------------------------------------------------
__global__ __launch_bounds__(256) void hist_kernel(const int* __restrict__ rows,
                                                   int* __restrict__ cnt) {
  const int r = blockIdx.y;
  const int e = blockIdx.x * 256 + threadIdx.x;
  atomicAdd(&cnt[r * N_ + rows[(size_t)r * E_ + e]], 1);
}

// ---------------------------------------------------------------------------
// K3a: per-block (1024-elem) exclusive scan of cnt -> part, block sums -> bsum
// ---------------------------------------------------------------------------
__global__ __launch_bounds__(256) void scanA(const int* __restrict__ cnt,
                                             int* __restrict__ part,
                                             int* __restrict__ bsum) {
  __shared__ int s[256];
  const int t = threadIdx.x;
  const int base = blockIdx.x * 1024 + t * 4;
  int v0 = 0, v1 = 0, v2 = 0, v3 = 0;
  if (base + 3 < RT) {
    const int4 c = *(const int4*)(cnt + base);
    v0 = c.x; v1 = c.y; v2 = c.z; v3 = c.w;
  } else {
    if (base + 0 < RT) v0 = cnt[base + 0];
    if (base + 1 < RT) v1 = cnt[base + 1];
    if (base + 2 < RT) v2 = cnt[base + 2];
  }
  const int tsum = v0 + v1 + v2 + v3;
  s[t] = tsum;
  __syncthreads();
  for (int off = 1; off < 256; off <<= 1) {
    const int x = s[t];
    const int y = (t >= off) ? s[t - off] : 0;
    __syncthreads();
    s[t] = x + y;
    __syncthreads();
  }
  if (t == 255) bsum[blockIdx.x] = s[255];
  const int e0 = s[t] - tsum;
  const int e1 = e0 + v0, e2 = e1 + v1, e3 = e2 + v2;
  if (base + 3 < RT) {
    *(int4*)(part + base) = make_int4(e0, e1, e2, e3);
  } else {
    if (base + 0 < RT) part[base + 0] = e0;
    if (base + 1 < RT) part[base + 1] = e1;
    if (base + 2 < RT) part[base + 2] = e2;
  }
}

// ---------------------------------------------------------------------------
// K3b: exclusive scan of the 147 block sums (single block, nb <= 256)
// ---------------------------------------------------------------------------
__global__ __launch_bounds__(256) void scanB(int* __restrict__ bsum, int nb) {
  __shared__ int s[256];
  const int t = threadIdx.x;
  const int v = (t < nb) ? bsum[t] : 0;
  s[t] = v;
  __syncthreads();
  for (int off = 1; off < 256; off <<= 1) {
    const int x = s[t];
    const int y = (t >= off) ? s[t - off] : 0;
    __syncthreads();
    s[t] = x + y;
    __syncthreads();
  }
  if (t < nb) bsum[t] = s[t] - v;  // exclusive
}

// ---------------------------------------------------------------------------
// K3c: cursor[i] = part[i] + bsum[i>>10]   (global exclusive row offsets)
// ---------------------------------------------------------------------------
__global__ __launch_bounds__(256) void scanC(const int* __restrict__ part,
                                             const int* __restrict__ bsum,
                                             int* __restrict__ cursor) {
  const int i = blockIdx.x * 256 + threadIdx.x;
  if (i < RT) cursor[i] = part[i] + bsum[i >> 10];
}

// ---------------------------------------------------------------------------
// K4: scatter edges into row-grouped order, ILP-8.
// Round-9 counters: 185 us, VALUBusy 0.4%, WRITE 154MB (64B-line amp of 8B
// writes -- unavoidable); stall = per-edge serial chain atomicAdd(return!)
// -> dependent store, 1 edge/thread. Fix: 8 edges/thread, issue all 8
// atomics before any dependent store (same ILP cure as gather).
// ---------------------------------------------------------------------------
__global__ __launch_bounds__(256) void scatter_kernel(const int* __restrict__ rows,
                                                      const int* __restrict__ cols,
                                                      const float* __restrict__ vals,
                                                      int* __restrict__ cursor,
                                                      int2* __restrict__ edges) {
  const int r = blockIdx.y;
  const int gt = blockIdx.x * 256 + threadIdx.x;
  const int e0 = gt * 8;
  if (e0 >= E_) return;
  const size_t eb = (size_t)r * E_ + e0;

  int rw[8];
  *(int4*)(rw + 0) = *(const int4*)(rows + eb + 0);
  *(int4*)(rw + 4) = *(const int4*)(rows + eb + 4);

  int* cur = cursor + r * N_;
  // 8 independent atomics in flight (each returns its reserved slot)
  const int p0 = atomicAdd(&cur[rw[0]], 1);
  const int p1 = atomicAdd(&cur[rw[1]], 1);
  const int p2 = atomicAdd(&cur[rw[2]], 1);
  const int p3 = atomicAdd(&cur[rw[3]], 1);
  const int p4 = atomicAdd(&cur[rw[4]], 1);
  const int p5 = atomicAdd(&cur[rw[5]], 1);
  const int p6 = atomicAdd(&cur[rw[6]], 1);
  const int p7 = atomicAdd(&cur[rw[7]], 1);

  int cl[8];
  *(int4*)(cl + 0) = *(const int4*)(cols + eb + 0);
  *(int4*)(cl + 4) = *(const int4*)(cols + eb + 4);
  float vl[8];
  *(float4*)(vl + 0) = *(const float4*)(vals + eb + 0);
  *(float4*)(vl + 4) = *(const float4*)(vals + eb + 4);

  edges[p0] = make_int2(cl[0], __float_as_int(vl[0]));
  edges[p1] = make_int2(cl[1], __float_as_int(vl[1]));
  edges[p2] = make_int2(cl[2], __float_as_int(vl[2]));
  edges[p3] = make_int2(cl[3], __float_as_int(vl[3]));
  edges[p4] = make_int2(cl[4], __float_as_int(vl[4]));
  edges[p5] = make_int2(cl[5], __float_as_int(vl[5]));
  edges[p6] = make_int2(cl[6], __float_as_int(vl[6]));
  edges[p7] = make_int2(cl[7], __float_as_int(vl[7]));
}

// ---------------------------------------------------------------------------
// K5: wave-per-row gather, 8-deep software pipeline (round-9: fell out of
// top-5, <183us as predicted; unchanged).
// ---------------------------------------------------------------------------
__global__ __launch_bounds__(256) void gather_kernel(const int2* __restrict__ edges,
                                                     const int* __restrict__ cursor,
                                                     const int* __restrict__ cnt,
                                                     const float* __restrict__ support,
                                                     const float* __restrict__ biases,
                                                     float* __restrict__ out) {
  const int rn = blockIdx.x * 4 + (threadIdx.x >> 6);
  if (rn >= RT) return;
  const int lane = threadIdx.x & 63;
  const int r = rn / N_;
  const int end = cursor[rn];
  int e = end - cnt[rn];
  const float* sup = support + (size_t)r * N_ * DOUT + lane;

  float a0 = biases[r * DOUT + lane];
  float a1 = 0.f;

  for (; e + 8 <= end; e += 8) {
    const int2 d0 = edges[e + 0];
    const int2 d1 = edges[e + 1];
    const int2 d2 = edges[e + 2];
    const int2 d3 = edges[e + 3];
    const int2 d4 = edges[e + 4];
    const int2 d5 = edges[e + 5];
    const int2 d6 = edges[e + 6];
    const int2 d7 = edges[e + 7];
    const float s0 = sup[(size_t)(unsigned)d0.x << 6];
    const float s1 = sup[(size_t)(unsigned)d1.x << 6];
    const float s2 = sup[(size_t)(unsigned)d2.x << 6];
    const float s3 = sup[(size_t)(unsigned)d3.x << 6];
    const float s4 = sup[(size_t)(unsigned)d4.x << 6];
    const float s5 = sup[(size_t)(unsigned)d5.x << 6];
    const float s6 = sup[(size_t)(unsigned)d6.x << 6];
    const float s7 = sup[(size_t)(unsigned)d7.x << 6];
    a0 = fmaf(__int_as_float(d0.y), s0, a0);
    a1 = fmaf(__int_as_float(d1.y), s1, a1);
    a0 = fmaf(__int_as_float(d2.y), s2, a0);
    a1 = fmaf(__int_as_float(d3.y), s3, a1);
    a0 = fmaf(__int_as_float(d4.y), s4, a0);
    a1 = fmaf(__int_as_float(d5.y), s5, a1);
    a0 = fmaf(__int_as_float(d6.y), s6, a0);
    a1 = fmaf(__int_as_float(d7.y), s7, a1);
  }
  for (; e < end; ++e) {
    const int2 ed = edges[e];
    a0 = fmaf(__int_as_float(ed.y), sup[(size_t)(unsigned)ed.x << 6], a0);
  }
  out[(size_t)rn * DOUT + lane] = a0 + a1;
}

// ---------------------------------------------------------------------------
// K6: softmax over relations + weighted sum
// ---------------------------------------------------------------------------
__global__ __launch_bounds__(256) void attn_kernel(const float* __restrict__ out,
                                                   const float* __restrict__ att_w,
                                                   const float* __restrict__ att_b,
                                                   float* __restrict__ dst) {
  const int node = blockIdx.x * 4 + (threadIdx.x >> 6);
  const int lane = threadIdx.x & 63;
  if (node >= N_) return;
  const float o0 = out[((size_t)0 * N_ + node) * DOUT + lane];
  const float o1 = out[((size_t)1 * N_ + node) * DOUT + lane];
  const float o2 = out[((size_t)2 * N_ + node) * DOUT + lane];
  const float aw = att_w[lane];
  float s0 = o0 * aw, s1 = o1 * aw, s2 = o2 * aw;
#pragma unroll
  for (int off = 32; off > 0; off >>= 1) {
    s0 += __shfl_xor(s0, off, 64);
    s1 += __shfl_xor(s1, off, 64);
    s2 += __shfl_xor(s2, off, 64);
  }
  const float ab = att_b[0];
  s0 += ab; s1 += ab; s2 += ab;
  const float m = fmaxf(s0, fmaxf(s1, s2));
  const float e0 = expf(s0 - m), e1 = expf(s1 - m), e2 = expf(s2 - m);
  const float inv = 1.f / (e0 + e1 + e2);
  const float w0 = e0 * inv, w1 = e1 * inv, w2 = e2 * inv;
  dst[(size_t)node * DOUT + lane] = w0 * o0 + w1 * o1 + w2 * o2;
  if (lane < 3) {
    const float w = (lane == 0) ? w0 : ((lane == 1) ? w1 : w2);
    dst[(size_t)N_ * DOUT + (size_t)node * 3 + lane] = w;
  }
}

extern "C" void kernel_launch(void* const* d_in, const int* in_sizes, int n_in,
                              void* d_out, int out_size, void* d_ws, size_t ws_size,
                              hipStream_t stream) {
  const int* adj_rows   = (const int*)d_in[0];
  const int* adj_cols   = (const int*)d_in[1];
  const float* adj_vals = (const float*)d_in[2];
  const float* X        = (const float*)d_in[3];
  const float* W        = (const float*)d_in[4];
  const float* biases   = (const float*)d_in[5];
  const float* att_w    = (const float*)d_in[6];
  const float* att_b    = (const float*)d_in[7];

  // workspace layout (all 16B-aligned)
  char* p = (char*)d_ws;
  float* support = (float*)p;            p += (size_t)R_ * N_ * DOUT * 4;  // 38.4 MB
  float* out     = (float*)p;            p += (size_t)R_ * N_ * DOUT * 4;  // 38.4 MB
  int2*  edges   = (int2*)p;             p += (size_t)R_ * E_ * 8;         // 19.2 MB
  int*   cnt     = (int*)p;              p += RT * 4;
  int*   part    = (int*)p;              p += RT * 4;
  int*   cursor  = (int*)p;              p += RT * 4;
  int*   bsum    = (int*)p;              p += 1024;

  hipMemsetAsync(cnt, 0, RT * sizeof(int), stream);

  dim3 ge(E_ / 256, R_);
  hist_kernel<<<ge, 256, 0, stream>>>(adj_rows, cnt);
  scanA<<<SCAN_NB, 256, 0, stream>>>(cnt, part, bsum);
  scanB<<<1, 256, 0, stream>>>(bsum, SCAN_NB);
  scanC<<<(RT + 255) / 256, 256, 0, stream>>>(part, bsum, cursor);

  dim3 gs8((E_ / 8 + 255) / 256, R_);
  scatter_kernel<<<gs8, 256, 0, stream>>>(adj_rows, adj_cols, adj_vals, cursor, edges);

  dim3 gg((N_ + 255) / 256, R_);
  gemm_kernel<<<gg, 256, 0, stream>>>(X, W, support);

  gather_kernel<<<(RT + 3) / 4, 256, 0, stream>>>(edges, cursor, cnt, support, biases, out);

  attn_kernel<<<(N_ + 3) / 4, 256, 0, stream>>>(out, att_w, att_b, (float*)d_out);
}

// Round 13
// 415.485 us; speedup vs baseline: 1.4571x; 1.4571x over previous
//
#include <hip/hip_runtime.h>

#define R_ 3
#define N_ 50000
#define E_ 800000
#define DIN 128
#define DOUT 64
#define RT (R_ * N_)        // 150000 output rows total

#define BK_SH 7
#define BK_ROWS 128                      // rows per bucket
#define NBKT ((N_ + BK_ROWS - 1) / BK_ROWS)  // 391 buckets per relation
#define NBT (NBKT * R_)                  // 1173 buckets total
#define CHUNK 8192                       // edges per binning block
#define NCH ((E_ + CHUNK - 1) / CHUNK)   // 98 blocks per relation
#define EPT (CHUNK / 256)                // 32 edges per thread

// ---------------------------------------------------------------------------
// K1: support[r] = X[r] @ W[r]   (fp32 vector GEMM, M=50000, K=128, N=64)
// ---------------------------------------------------------------------------
__global__ __launch_bounds__(256) void gemm_kernel(const float* __restrict__ X,
                                                   const float* __restrict__ W,
                                                   float* __restrict__ support) {
  const int r = blockIdx.y;
  const int base = blockIdx.x * 256;
  const int t = threadIdx.x;

  __shared__ float x_s[32 * 258];

  const float* Xr = X + (size_t)r * N_ * DIN;
  const float* Wr = W + (size_t)r * DIN * DOUT;

  float acc[DOUT];
#pragma unroll
  for (int o = 0; o < DOUT; ++o) acc[o] = 0.f;

  for (int k0 = 0; k0 < DIN; k0 += 32) {
    __syncthreads();
#pragma unroll
    for (int i = 0; i < 8; ++i) {
      int rl = i * 32 + (t >> 3);
      int k4 = (t & 7) * 4;
      int rg = base + rl;
      if (rg > N_ - 1) rg = N_ - 1;
      const float4 v = *(const float4*)(Xr + (size_t)rg * DIN + k0 + k4);
      x_s[(k4 + 0) * 258 + rl] = v.x;
      x_s[(k4 + 1) * 258 + rl] = v.y;
      x_s[(k4 + 2) * 258 + rl] = v.z;
      x_s[(k4 + 3) * 258 + rl] = v.w;
    }
    __syncthreads();
#pragma unroll 4
    for (int kk = 0; kk < 32; ++kk) {
      const float xv = x_s[kk * 258 + t];
      const float* wrow = Wr + (size_t)(k0 + kk) * DOUT;  // wave-uniform -> s_load
#pragma unroll
      for (int o = 0; o < DOUT; ++o) acc[o] = fmaf(wrow[o], xv, acc[o]);
    }
  }

  const int row = base + t;
  if (row < N_) {
    float* op = support + ((size_t)r * N_ + row) * DOUT;
#pragma unroll
    for (int o = 0; o < DOUT; o += 4) {
      float4 v = {acc[o], acc[o + 1], acc[o + 2], acc[o + 3]};
      *(float4*)(op + o) = v;
    }
  }
}

// ---------------------------------------------------------------------------
// K2: bucket histogram. LDS per-block hist of 128-row buckets, then one
// global atomic per (block,bucket): 460K atomics instead of 2.4M.
// ---------------------------------------------------------------------------
__global__ __launch_bounds__(256) void bhist_kernel(const int* __restrict__ rows,
                                                    int* __restrict__ btot) {
  __shared__ int h[NBKT];
  const int r = blockIdx.y;
  const int cb = blockIdx.x * CHUNK;
  const int t = threadIdx.x;
  for (int i = t; i < NBKT; i += 256) h[i] = 0;
  __syncthreads();
  const int* rr = rows + (size_t)r * E_;
#pragma unroll
  for (int i = 0; i < EPT; ++i) {
    const int e = cb + i * 256 + t;
    if (e < E_) atomicAdd(&h[rr[e] >> BK_SH], 1);
  }
  __syncthreads();
  for (int i = t; i < NBKT; i += 256)
    if (h[i]) atomicAdd(&btot[r * NBKT + i], h[i]);
}

// ---------------------------------------------------------------------------
// K3: single-block exclusive scan of the 1173 bucket totals -> bstart, bcur.
// ---------------------------------------------------------------------------
__global__ __launch_bounds__(256) void bscan_kernel(const int* __restrict__ btot,
                                                    int* __restrict__ bstart,
                                                    int* __restrict__ bcur) {
  __shared__ int s[256];
  const int t = threadIdx.x;
  int pre[5];
  int sum = 0;
#pragma unroll
  for (int j = 0; j < 5; ++j) {
    const int idx = t * 5 + j;
    const int x = (idx < NBT) ? btot[idx] : 0;
    pre[j] = sum;
    sum += x;
  }
  s[t] = sum;
  __syncthreads();
  for (int off = 1; off < 256; off <<= 1) {
    const int x = s[t];
    const int y = (t >= off) ? s[t - off] : 0;
    __syncthreads();
    s[t] = x + y;
    __syncthreads();
  }
  const int base = s[t] - sum;  // exclusive over thread chunks
#pragma unroll
  for (int j = 0; j < 5; ++j) {
    const int idx = t * 5 + j;
    if (idx < NBT) {
      const int st = base + pre[j];
      bstart[idx] = st;
      bcur[idx] = st;
    }
  }
}

// ---------------------------------------------------------------------------
// K4: bin pass 1 — rank edges within block via LDS atomics, reserve a
// per-(block,bucket) base once, write {rowlocal|col, val} in contiguous
// per-bucket runs (~168B avg) -> write amplification ~1.3x, not 8x.
// ---------------------------------------------------------------------------
__global__ __launch_bounds__(256) void binsort1_kernel(const int* __restrict__ rows,
                                                       const int* __restrict__ cols,
                                                       const float* __restrict__ vals,
                                                       int* __restrict__ bcur,
                                                       int2* __restrict__ etmp) {
  __shared__ int h[NBKT];
  __shared__ int base[NBKT];
  const int r = blockIdx.y;
  const int cb = blockIdx.x * CHUNK;
  const int t = threadIdx.x;
  for (int i = t; i < NBKT; i += 256) h[i] = 0;
  __syncthreads();
  const size_t eo = (size_t)r * E_;

  int pk[EPT];  // rank(13b)<<16 | rowlocal(7b)<<9 | bucket(9b); -1 = invalid
#pragma unroll
  for (int i = 0; i < EPT; ++i) {
    const int e = cb + i * 256 + t;
    pk[i] = -1;
    if (e < E_) {
      const int row = rows[eo + e];
      const int b = row >> BK_SH;
      const int rk = atomicAdd(&h[b], 1);  // < CHUNK = 8192
      pk[i] = (rk << 16) | ((row & (BK_ROWS - 1)) << 9) | b;
    }
  }
  __syncthreads();
  for (int i = t; i < NBKT; i += 256)
    base[i] = h[i] ? atomicAdd(&bcur[r * NBKT + i], h[i]) : 0;
  __syncthreads();
#pragma unroll
  for (int i = 0; i < EPT; ++i) {
    if (pk[i] >= 0) {
      const int e = cb + i * 256 + t;
      const int b = pk[i] & 511;
      const int rl = (pk[i] >> 9) & (BK_ROWS - 1);
      const int rk = pk[i] >> 16;
      etmp[base[b] + rk] = make_int2((rl << 16) | cols[eo + e],
                                     __float_as_int(vals[eo + e]));
    }
  }
}

// ---------------------------------------------------------------------------
// K5: bin pass 2 — one block per bucket. LDS hist+scan of 128 rows emits
// row_start/row_cnt directly (no global row scan), then re-rank and write
// final row-grouped records into the bucket's private ~16KB window
// (single-XCD L2-resident -> lines coalesce before eviction).
// ---------------------------------------------------------------------------
__global__ __launch_bounds__(256) void binsort2_kernel(const int2* __restrict__ etmp,
                                                       const int* __restrict__ bstart,
                                                       const int* __restrict__ btot,
                                                       int2* __restrict__ edges,
                                                       int* __restrict__ row_start,
                                                       int* __restrict__ row_cnt) {
  __shared__ int h[BK_ROWS];
  __shared__ int ex[BK_ROWS];
  const int b = blockIdx.x;  // 0..NBT-1
  const int r = b / NBKT;
  const int lb = b % NBKT;
  const int t = threadIdx.x;
  const int beg = bstart[b];
  const int num = btot[b];

  if (t < BK_ROWS) h[t] = 0;
  __syncthreads();
  for (int i = t; i < num; i += 256)
    atomicAdd(&h[etmp[beg + i].x >> 16], 1);
  __syncthreads();

  const int myh = (t < BK_ROWS) ? h[t] : 0;
  if (t < BK_ROWS) ex[t] = myh;
  __syncthreads();
  for (int off = 1; off < BK_ROWS; off <<= 1) {
    int x = 0;
    if (t < BK_ROWS) {
      x = ex[t];
      if (t >= off) x += ex[t - off];
    }
    __syncthreads();
    if (t < BK_ROWS) ex[t] = x;
    __syncthreads();
  }
  // ex = inclusive scan; exclusive = ex - myh
  const int rows_here = min(BK_ROWS, N_ - lb * BK_ROWS);
  if (t < rows_here) {
    const int rn = r * N_ + lb * BK_ROWS + t;
    row_start[rn] = beg + ex[t] - myh;
    row_cnt[rn] = myh;
  }
  __syncthreads();
  if (t < BK_ROWS) {
    ex[t] = ex[t] - myh;  // exclusive offsets for writing
    h[t] = 0;             // reuse as rank counters
  }
  __syncthreads();
  for (int i = t; i < num; i += 256) {
    const int2 e = etmp[beg + i];
    const int rl = e.x >> 16;
    const int rk = atomicAdd(&h[rl], 1);
    edges[beg + ex[rl] + rk] = make_int2(e.x & 0xFFFF, e.y);
  }
}

// ---------------------------------------------------------------------------
// K6: wave-per-row gather, 8-deep software pipeline (round-9 verified).
// ---------------------------------------------------------------------------
__global__ __launch_bounds__(256) void gather_kernel(const int2* __restrict__ edges,
                                                     const int* __restrict__ row_start,
                                                     const int* __restrict__ row_cnt,
                                                     const float* __restrict__ support,
                                                     const float* __restrict__ biases,
                                                     float* __restrict__ out) {
  const int rn = blockIdx.x * 4 + (threadIdx.x >> 6);
  if (rn >= RT) return;
  const int lane = threadIdx.x & 63;
  const int r = rn / N_;
  int e = row_start[rn];
  const int end = e + row_cnt[rn];
  const float* sup = support + (size_t)r * N_ * DOUT + lane;

  float a0 = biases[r * DOUT + lane];
  float a1 = 0.f;

  for (; e + 8 <= end; e += 8) {
    const int2 d0 = edges[e + 0];
    const int2 d1 = edges[e + 1];
    const int2 d2 = edges[e + 2];
    const int2 d3 = edges[e + 3];
    const int2 d4 = edges[e + 4];
    const int2 d5 = edges[e + 5];
    const int2 d6 = edges[e + 6];
    const int2 d7 = edges[e + 7];
    const float s0 = sup[(size_t)(unsigned)d0.x << 6];
    const float s1 = sup[(size_t)(unsigned)d1.x << 6];
    const float s2 = sup[(size_t)(unsigned)d2.x << 6];
    const float s3 = sup[(size_t)(unsigned)d3.x << 6];
    const float s4 = sup[(size_t)(unsigned)d4.x << 6];
    const float s5 = sup[(size_t)(unsigned)d5.x << 6];
    const float s6 = sup[(size_t)(unsigned)d6.x << 6];
    const float s7 = sup[(size_t)(unsigned)d7.x << 6];
    a0 = fmaf(__int_as_float(d0.y), s0, a0);
    a1 = fmaf(__int_as_float(d1.y), s1, a1);
    a0 = fmaf(__int_as_float(d2.y), s2, a0);
    a1 = fmaf(__int_as_float(d3.y), s3, a1);
    a0 = fmaf(__int_as_float(d4.y), s4, a0);
    a1 = fmaf(__int_as_float(d5.y), s5, a1);
    a0 = fmaf(__int_as_float(d6.y), s6, a0);
    a1 = fmaf(__int_as_float(d7.y), s7, a1);
  }
  for (; e < end; ++e) {
    const int2 ed = edges[e];
    a0 = fmaf(__int_as_float(ed.y), sup[(size_t)(unsigned)ed.x << 6], a0);
  }
  out[(size_t)rn * DOUT + lane] = a0 + a1;
}

// ---------------------------------------------------------------------------
// K7: softmax over relations + weighted sum
// ---------------------------------------------------------------------------
__global__ __launch_bounds__(256) void attn_kernel(const float* __restrict__ out,
                                                   const float* __restrict__ att_w,
                                                   const float* __restrict__ att_b,
                                                   float* __restrict__ dst) {
  const int node = blockIdx.x * 4 + (threadIdx.x >> 6);
  const int lane = threadIdx.x & 63;
  if (node >= N_) return;
  const float o0 = out[((size_t)0 * N_ + node) * DOUT + lane];
  const float o1 = out[((size_t)1 * N_ + node) * DOUT + lane];
  const float o2 = out[((size_t)2 * N_ + node) * DOUT + lane];
  const float aw = att_w[lane];
  float s0 = o0 * aw, s1 = o1 * aw, s2 = o2 * aw;
#pragma unroll
  for (int off = 32; off > 0; off >>= 1) {
    s0 += __shfl_xor(s0, off, 64);
    s1 += __shfl_xor(s1, off, 64);
    s2 += __shfl_xor(s2, off, 64);
  }
  const float ab = att_b[0];
  s0 += ab; s1 += ab; s2 += ab;
  const float m = fmaxf(s0, fmaxf(s1, s2));
  const float e0 = expf(s0 - m), e1 = expf(s1 - m), e2 = expf(s2 - m);
  const float inv = 1.f / (e0 + e1 + e2);
  const float w0 = e0 * inv, w1 = e1 * inv, w2 = e2 * inv;
  dst[(size_t)node * DOUT + lane] = w0 * o0 + w1 * o1 + w2 * o2;
  if (lane < 3) {
    const float w = (lane == 0) ? w0 : ((lane == 1) ? w1 : w2);
    dst[(size_t)N_ * DOUT + (size_t)node * 3 + lane] = w;
  }
}

extern "C" void kernel_launch(void* const* d_in, const int* in_sizes, int n_in,
                              void* d_out, int out_size, void* d_ws, size_t ws_size,
                              hipStream_t stream) {
  const int* adj_rows   = (const int*)d_in[0];
  const int* adj_cols   = (const int*)d_in[1];
  const float* adj_vals = (const float*)d_in[2];
  const float* X        = (const float*)d_in[3];
  const float* W        = (const float*)d_in[4];
  const float* biases   = (const float*)d_in[5];
  const float* att_w    = (const float*)d_in[6];
  const float* att_b    = (const float*)d_in[7];

  // workspace layout (all 16B-aligned). etmp ALIASES out: pass1 writes it,
  // pass2 reads it, and only later does gather write out (etmp dead by then).
  char* p = (char*)d_ws;
  float* support   = (float*)p;  p += (size_t)R_ * N_ * DOUT * 4;  // 38.4 MB
  float* out       = (float*)p;  p += (size_t)R_ * N_ * DOUT * 4;  // 38.4 MB
  int2*  edges     = (int2*)p;   p += (size_t)R_ * E_ * 8;         // 19.2 MB
  int*   row_start = (int*)p;    p += RT * 4;
  int*   row_cnt   = (int*)p;    p += RT * 4;
  int*   btot      = (int*)p;    p += ((NBT + 3) & ~3) * 4;
  int*   bstart    = (int*)p;    p += ((NBT + 3) & ~3) * 4;
  int*   bcur      = (int*)p;    p += ((NBT + 3) & ~3) * 4;
  int2*  etmp      = (int2*)out;

  hipMemsetAsync(btot, 0, NBT * sizeof(int), stream);

  dim3 gb(NCH, R_);
  bhist_kernel<<<gb, 256, 0, stream>>>(adj_rows, btot);
  bscan_kernel<<<1, 256, 0, stream>>>(btot, bstart, bcur);
  binsort1_kernel<<<gb, 256, 0, stream>>>(adj_rows, adj_cols, adj_vals, bcur, etmp);
  binsort2_kernel<<<NBT, 256, 0, stream>>>(etmp, bstart, btot, edges, row_start, row_cnt);

  dim3 gg((N_ + 255) / 256, R_);
  gemm_kernel<<<gg, 256, 0, stream>>>(X, W, support);

  gather_kernel<<<(RT + 3) / 4, 256, 0, stream>>>(edges, row_start, row_cnt, support, biases, out);

  attn_kernel<<<(N_ + 3) / 4, 256, 0, stream>>>(out, att_w, att_b, (float*)d_out);
}